// Round 2
// baseline (305.653 us; speedup 1.0000x reference)
//
#include <hip/hip_runtime.h>
#include <hip/hip_bf16.h>

typedef __bf16 bf16_t;
typedef __bf16 bf16x8 __attribute__((ext_vector_type(8)));
typedef __bf16 bf16x4 __attribute__((ext_vector_type(4)));
typedef float floatx4 __attribute__((ext_vector_type(4)));

#define MFMA16(a, b, c) __builtin_amdgcn_mfma_f32_16x16x32_bf16(a, b, c, 0, 0, 0)

// ---------------------------------------------------------------------------
// cast_f32_bf16: x (fp32) -> xb (bf16), 4 elems/thread
// ---------------------------------------------------------------------------
__global__ void cast_f32_bf16(const float* __restrict__ in, bf16_t* __restrict__ out) {
    int i = blockIdx.x * blockDim.x + threadIdx.x;
    float4 v = ((const float4*)in)[i];
    bf16x4 o = {(bf16_t)v.x, (bf16_t)v.y, (bf16_t)v.z, (bf16_t)v.w};
    *(bf16x4*)(out + (size_t)i * 4) = o;
}

// ---------------------------------------------------------------------------
// prep_w (fp32 in, bf16 out):
//   wqkvT[n][k] = w_qkv[k][n] * (n<384 ? 0.125 : 1)   (fold 1/sqrt(64) into Q)
//   wprojT[n][k] = w_proj[k][n]
// ---------------------------------------------------------------------------
__global__ void prep_w(const float* __restrict__ w_qkv, const float* __restrict__ w_proj,
                       bf16_t* __restrict__ wqkvT, bf16_t* __restrict__ wprojT) {
    __shared__ float tile[32][33];
    const int which = blockIdx.z;             // 0: w_qkv, 1: w_proj
    const int Nd = which ? 384 : 1152;
    const int n0 = blockIdx.x * 32, k0 = blockIdx.y * 32;
    if (n0 >= Nd) return;
    const float* in = which ? w_proj : w_qkv;
    bf16_t* out = which ? wprojT : wqkvT;
    const int tx = threadIdx.x & 31, ty = threadIdx.x >> 5;  // ty in [0,8)
#pragma unroll
    for (int i = 0; i < 4; i++)
        tile[ty + i * 8][tx] = in[(size_t)(k0 + ty + i * 8) * Nd + n0 + tx];
    __syncthreads();
#pragma unroll
    for (int i = 0; i < 4; i++) {
        int n = n0 + ty + i * 8;
        float v = tile[tx][ty + i * 8];
        if (!which && n < 384) v *= 0.125f;
        out[(size_t)n * 384 + k0 + tx] = (bf16_t)v;
    }
}

// ---------------------------------------------------------------------------
// vt_kernel: Vt[b][h][d][t] = qkv[b][t][768 + h*64 + d]  (transpose V for PV B-frags)
// ---------------------------------------------------------------------------
__global__ void vt_kernel(const bf16_t* __restrict__ qkv, bf16_t* __restrict__ Vt) {
    __shared__ unsigned short tile[32][33];
    const int t0 = blockIdx.x * 32, d0 = blockIdx.y * 32;
    const int bh = blockIdx.z;  // b*6+h
    const int b = bh / 6, h = bh % 6;
    const int tx = threadIdx.x & 31, ty = threadIdx.x >> 5;
    const unsigned short* src = (const unsigned short*)qkv;
    unsigned short* dst = (unsigned short*)Vt;
#pragma unroll
    for (int i = 0; i < 4; i++)
        tile[ty + i * 8][tx] =
            src[((size_t)b * 2048 + t0 + ty + i * 8) * 1152 + 768 + h * 64 + d0 + tx];
    __syncthreads();
#pragma unroll
    for (int i = 0; i < 4; i++)
        dst[((size_t)bh * 64 + d0 + ty + i * 8) * 2048 + t0 + tx] = tile[tx][ty + i * 8];
}

// ---------------------------------------------------------------------------
// gemm_bt: C[M][N] = A[M][K] @ Bt[N][K]^T (+bias). 128x128 tile, BK=32, 4 waves.
// Wave (wm,wn) computes 64x64 via 4x4 grid of 16x16x32 MFMAs.
// LDS rows padded to 40 bf16 (80B = 5*16B: keeps 16B alignment, 2-way banks = free).
// F32OUT: write fp32 (final projection) vs bf16 (intermediate).
// ---------------------------------------------------------------------------
template <bool F32OUT>
__global__ __launch_bounds__(256, 2)
void gemm_bt(const bf16_t* __restrict__ A, const bf16_t* __restrict__ Bt,
             void* __restrict__ Cv, int M, int N, int K, const float* __restrict__ bias) {
    constexpr int LDA = 40;
    __shared__ bf16_t As[128 * LDA];
    __shared__ bf16_t Bs[128 * LDA];
    const int tid = threadIdx.x;
    const int wave = tid >> 6, lane = tid & 63;
    const int wm = wave >> 1, wn = wave & 1;
    const int quad = lane >> 4, l16 = lane & 15;
    const int row0 = blockIdx.y * 128, col0 = blockIdx.x * 128;

    floatx4 acc[4][4];
#pragma unroll
    for (int i = 0; i < 4; i++)
#pragma unroll
        for (int j = 0; j < 4; j++) acc[i][j] = (floatx4){0.f, 0.f, 0.f, 0.f};

    for (int k0 = 0; k0 < K; k0 += 32) {
#pragma unroll
        for (int it = 0; it < 2; it++) {
            int c = tid + it * 256;            // 512 chunks of 16B per tile
            int r = c >> 2, c8 = (c & 3) * 8;
            uint4 va = *(const uint4*)(A + (size_t)(row0 + r) * K + k0 + c8);
            *(uint4*)(As + r * LDA + c8) = va;
            uint4 vb = *(const uint4*)(Bt + (size_t)(col0 + r) * K + k0 + c8);
            *(uint4*)(Bs + r * LDA + c8) = vb;
        }
        __syncthreads();
        bf16x8 af[4], bfr[4];
#pragma unroll
        for (int i = 0; i < 4; i++)
            af[i] = *(const bf16x8*)(As + (wm * 64 + i * 16 + l16) * LDA + quad * 8);
#pragma unroll
        for (int j = 0; j < 4; j++)
            bfr[j] = *(const bf16x8*)(Bs + (wn * 64 + j * 16 + l16) * LDA + quad * 8);
#pragma unroll
        for (int i = 0; i < 4; i++)
#pragma unroll
            for (int j = 0; j < 4; j++) acc[i][j] = MFMA16(af[i], bfr[j], acc[i][j]);
        __syncthreads();
    }
#pragma unroll
    for (int i = 0; i < 4; i++) {
#pragma unroll
        for (int j = 0; j < 4; j++) {
            int col = col0 + wn * 64 + j * 16 + l16;
            float bv = bias ? bias[col] : 0.0f;
#pragma unroll
            for (int r = 0; r < 4; r++) {
                int row = row0 + wm * 64 + i * 16 + quad * 4 + r;
                float v = acc[i][j][r] + bv;
                if (F32OUT)
                    ((float*)Cv)[(size_t)row * N + col] = v;
                else
                    ((bf16_t*)Cv)[(size_t)row * N + col] = (bf16_t)v;
            }
        }
    }
}

// ---------------------------------------------------------------------------
// attn_kernel: flash attention, causal. Block = (qt, h, b), 4 waves x 16 q-rows.
// Q pre-scaled by 1/8 (folded into weights). K tile [kv][d], V^T tile [d][kv] in LDS.
// C/D layout: col=lane&15, row=quad*4+reg. A layout: A[m=lane&15][k=quad*8+j].
// ---------------------------------------------------------------------------
__global__ __launch_bounds__(256, 2)
void attn_kernel(const bf16_t* __restrict__ qkv, const bf16_t* __restrict__ Vt,
                 bf16_t* __restrict__ attn_out) {
    constexpr int T = 2048, C3 = 1152, LDK = 72;
    const int qt = blockIdx.x, h = blockIdx.y, b = blockIdx.z;
    const int tid = threadIdx.x;
    const int wave = tid >> 6, lane = tid & 63;
    const int quad = lane >> 4, l16 = lane & 15;

    __shared__ bf16_t Ks[64 * LDK];
    __shared__ bf16_t Vs[64 * LDK];
    __shared__ bf16_t Ps[4][16 * LDK];

    // Q fragments held in registers for the whole kernel (A-operand layout)
    const int qrow = qt * 64 + wave * 16 + l16;
    const bf16_t* qp = qkv + ((size_t)b * T + qrow) * C3 + h * 64 + quad * 8;
    const bf16x8 qf0 = *(const bf16x8*)(qp);
    const bf16x8 qf1 = *(const bf16x8*)(qp + 32);

    floatx4 o[4];
#pragma unroll
    for (int nt = 0; nt < 4; nt++) o[nt] = (floatx4){0.f, 0.f, 0.f, 0.f};
    float m_run[4], l_run[4];
#pragma unroll
    for (int r = 0; r < 4; r++) { m_run[r] = -1e30f; l_run[r] = 0.f; }

    const bf16_t* kbase = qkv + (size_t)b * T * C3 + 384 + h * 64;
    const bf16_t* vbase = Vt + ((size_t)(b * 6 + h)) * 64 * T;

    for (int kt = 0; kt <= qt; kt++) {
        // stage K[kv][d] and V^T[d][kv] tiles (64x64 each) into LDS
#pragma unroll
        for (int it = 0; it < 2; it++) {
            int c = tid + it * 256;            // 512 chunks of 16B per tile
            int r = c >> 3, c8 = (c & 7) * 8;
            uint4 kv4 = *(const uint4*)(kbase + (size_t)(kt * 64 + r) * C3 + c8);
            *(uint4*)(Ks + r * LDK + c8) = kv4;
            uint4 vv4 = *(const uint4*)(vbase + (size_t)r * T + kt * 64 + c8);
            *(uint4*)(Vs + r * LDK + c8) = vv4;
        }
        __syncthreads();

        // S = Q @ K^T  (16 q-rows x 64 kv-cols per wave)
        floatx4 s[4];
#pragma unroll
        for (int nt = 0; nt < 4; nt++) {
            s[nt] = (floatx4){0.f, 0.f, 0.f, 0.f};
            bf16x8 kf0 = *(const bf16x8*)(Ks + (nt * 16 + l16) * LDK + quad * 8);
            bf16x8 kf1 = *(const bf16x8*)(Ks + (nt * 16 + l16) * LDK + 32 + quad * 8);
            s[nt] = MFMA16(qf0, kf0, s[nt]);
            s[nt] = MFMA16(qf1, kf1, s[nt]);
        }

        if (kt == qt) {  // causal mask, diagonal tile only
#pragma unroll
            for (int nt = 0; nt < 4; nt++)
#pragma unroll
                for (int r = 0; r < 4; r++) {
                    int kvl = nt * 16 + l16, ql = wave * 16 + quad * 4 + r;
                    if (kvl > ql) s[nt][r] = -1e30f;
                }
        }

        // online softmax (rows live on lanes of one quad; reduce across 16 lanes)
        float mx[4];
#pragma unroll
        for (int r = 0; r < 4; r++)
            mx[r] = fmaxf(fmaxf(s[0][r], s[1][r]), fmaxf(s[2][r], s[3][r]));
#pragma unroll
        for (int off = 8; off; off >>= 1)
#pragma unroll
            for (int r = 0; r < 4; r++) mx[r] = fmaxf(mx[r], __shfl_xor(mx[r], off));
        float alpha[4];
#pragma unroll
        for (int r = 0; r < 4; r++) {
            float mn = fmaxf(m_run[r], mx[r]);
            alpha[r] = __expf(m_run[r] - mn);
            m_run[r] = mn;
        }
        float rs[4] = {0.f, 0.f, 0.f, 0.f};
#pragma unroll
        for (int nt = 0; nt < 4; nt++)
#pragma unroll
            for (int r = 0; r < 4; r++) {
                float p = __expf(s[nt][r] - m_run[r]);
                s[nt][r] = p;
                rs[r] += p;
            }
#pragma unroll
        for (int off = 8; off; off >>= 1)
#pragma unroll
            for (int r = 0; r < 4; r++) rs[r] += __shfl_xor(rs[r], off);
#pragma unroll
        for (int r = 0; r < 4; r++) l_run[r] = l_run[r] * alpha[r] + rs[r];
#pragma unroll
        for (int nt = 0; nt < 4; nt++)
#pragma unroll
            for (int r = 0; r < 4; r++) o[nt][r] *= alpha[r];

        // P: C-layout -> LDS -> A-layout (per-wave region)
#pragma unroll
        for (int nt = 0; nt < 4; nt++)
#pragma unroll
            for (int r = 0; r < 4; r++)
                Ps[wave][(quad * 4 + r) * LDK + nt * 16 + l16] = (bf16_t)s[nt][r];
        __syncthreads();

        // O += P @ V
        bf16x8 pf0 = *(const bf16x8*)(&Ps[wave][l16 * LDK + quad * 8]);
        bf16x8 pf1 = *(const bf16x8*)(&Ps[wave][l16 * LDK + 32 + quad * 8]);
#pragma unroll
        for (int nt = 0; nt < 4; nt++) {
            bf16x8 vf0 = *(const bf16x8*)(Vs + (nt * 16 + l16) * LDK + quad * 8);
            bf16x8 vf1 = *(const bf16x8*)(Vs + (nt * 16 + l16) * LDK + 32 + quad * 8);
            o[nt] = MFMA16(pf0, vf0, o[nt]);
            o[nt] = MFMA16(pf1, vf1, o[nt]);
        }
        __syncthreads();
    }

    // epilogue: normalize and store to attn_out [B,T,C]
    float inv[4];
#pragma unroll
    for (int r = 0; r < 4; r++) inv[r] = 1.0f / l_run[r];
#pragma unroll
    for (int nt = 0; nt < 4; nt++)
#pragma unroll
        for (int r = 0; r < 4; r++) {
            int t = qt * 64 + wave * 16 + quad * 4 + r;
            attn_out[((size_t)b * T + t) * 384 + h * 64 + nt * 16 + l16] =
                (bf16_t)(o[nt][r] * inv[r]);
        }
}

// ---------------------------------------------------------------------------
extern "C" void kernel_launch(void* const* d_in, const int* in_sizes, int n_in,
                              void* d_out, int out_size, void* d_ws, size_t ws_size,
                              hipStream_t stream) {
    const float* x      = (const float*)d_in[0];  // [8,2048,384] fp32
    const float* w_qkv  = (const float*)d_in[1];  // [384,1152]  fp32
    const float* w_proj = (const float*)d_in[2];  // [384,384]   fp32
    const float* b_proj = (const float*)d_in[3];  // [384]       fp32
    float* out = (float*)d_out;                   // [8,2048,384] fp32

    bf16_t* ws = (bf16_t*)d_ws;
    bf16_t* wqkvT = ws;                                  // 1152*384
    bf16_t* wprojT = wqkvT + 1152 * 384;                 // 384*384
    bf16_t* xb = wprojT + 384 * 384;                     // 16384*384
    bf16_t* qkv = xb + (size_t)16384 * 384;              // 16384*1152
    bf16_t* Vt = qkv + (size_t)16384 * 1152;             // 48*64*2048
    bf16_t* attn = Vt + (size_t)48 * 64 * 2048;          // 16384*384
    // total ~77 MB of workspace

    hipLaunchKernelGGL(cast_f32_bf16, dim3(16384 * 384 / 4 / 256), dim3(256), 0, stream,
                       x, xb);
    hipLaunchKernelGGL(prep_w, dim3(36, 12, 2), dim3(256), 0, stream,
                       w_qkv, w_proj, wqkvT, wprojT);
    hipLaunchKernelGGL((gemm_bt<false>), dim3(9, 128), dim3(256), 0, stream,
                       xb, wqkvT, (void*)qkv, 16384, 1152, 384, (const float*)nullptr);
    hipLaunchKernelGGL(vt_kernel, dim3(64, 2, 48), dim3(256), 0, stream, qkv, Vt);
    hipLaunchKernelGGL(attn_kernel, dim3(32, 6, 8), dim3(256), 0, stream, qkv, Vt, attn);
    hipLaunchKernelGGL((gemm_bt<true>), dim3(3, 128), dim3(256), 0, stream,
                       attn, wprojT, (void*)out, 16384, 384, 384, b_proj);
}

// Round 3
// 222.889 us; speedup vs baseline: 1.3713x; 1.3713x over previous
//
#include <hip/hip_runtime.h>
#include <hip/hip_bf16.h>

typedef __bf16 bf16_t;
typedef __bf16 bf16x8 __attribute__((ext_vector_type(8)));
typedef __bf16 bf16x4 __attribute__((ext_vector_type(4)));
typedef float floatx4 __attribute__((ext_vector_type(4)));

#define MFMA16(a, b, c) __builtin_amdgcn_mfma_f32_16x16x32_bf16(a, b, c, 0, 0, 0)

#if __has_builtin(__builtin_amdgcn_exp2f)
#define EXP2F(x) __builtin_amdgcn_exp2f(x)
#else
#define EXP2F(x) __expf((x)*0.693147180559945f)
#endif

// async global->LDS, 16B per lane. LDS dest = wave-uniform base + lane*16.
__device__ __forceinline__ void async_copy16(const bf16_t* g, bf16_t* l) {
    __builtin_amdgcn_global_load_lds((const __attribute__((address_space(1))) void*)g,
                                     (__attribute__((address_space(3))) void*)l, 16, 0, 0);
}

// ---------------------------------------------------------------------------
// cast_f32_bf16: x (fp32) -> xb (bf16), 4 elems/thread
// ---------------------------------------------------------------------------
__global__ void cast_f32_bf16(const float* __restrict__ in, bf16_t* __restrict__ out) {
    int i = blockIdx.x * blockDim.x + threadIdx.x;
    float4 v = ((const float4*)in)[i];
    bf16x4 o = {(bf16_t)v.x, (bf16_t)v.y, (bf16_t)v.z, (bf16_t)v.w};
    *(bf16x4*)(out + (size_t)i * 4) = o;
}

// ---------------------------------------------------------------------------
// prep_w (fp32 in, bf16 out):
//   wqkvT[n][k] = w_qkv[k][n] * (n<384 ? 0.125*log2(e) : 1)
//   (folds softmax scale AND the exp->exp2 conversion into Q columns)
//   wprojT[n][k] = w_proj[k][n]
// ---------------------------------------------------------------------------
__global__ void prep_w(const float* __restrict__ w_qkv, const float* __restrict__ w_proj,
                       bf16_t* __restrict__ wqkvT, bf16_t* __restrict__ wprojT) {
    __shared__ float tile[32][33];
    const int which = blockIdx.z;             // 0: w_qkv, 1: w_proj
    const int Nd = which ? 384 : 1152;
    const int n0 = blockIdx.x * 32, k0 = blockIdx.y * 32;
    if (n0 >= Nd) return;
    const float* in = which ? w_proj : w_qkv;
    bf16_t* out = which ? wprojT : wqkvT;
    const int tx = threadIdx.x & 31, ty = threadIdx.x >> 5;  // ty in [0,8)
#pragma unroll
    for (int i = 0; i < 4; i++)
        tile[ty + i * 8][tx] = in[(size_t)(k0 + ty + i * 8) * Nd + n0 + tx];
    __syncthreads();
#pragma unroll
    for (int i = 0; i < 4; i++) {
        int n = n0 + ty + i * 8;
        float v = tile[tx][ty + i * 8];
        if (!which && n < 384) v *= 0.1803368851f;  // 0.125 * log2(e)
        out[(size_t)n * 384 + k0 + tx] = (bf16_t)v;
    }
}

// ---------------------------------------------------------------------------
// vt_kernel: Vt[b][h][d][t] = qkv[b][t][768 + h*64 + d]
// ---------------------------------------------------------------------------
__global__ void vt_kernel(const bf16_t* __restrict__ qkv, bf16_t* __restrict__ Vt) {
    __shared__ unsigned short tile[32][33];
    const int t0 = blockIdx.x * 32, d0 = blockIdx.y * 32;
    const int bh = blockIdx.z;  // b*6+h
    const int b = bh / 6, h = bh % 6;
    const int tx = threadIdx.x & 31, ty = threadIdx.x >> 5;
    const unsigned short* src = (const unsigned short*)qkv;
    unsigned short* dst = (unsigned short*)Vt;
#pragma unroll
    for (int i = 0; i < 4; i++)
        tile[ty + i * 8][tx] =
            src[((size_t)b * 2048 + t0 + ty + i * 8) * 1152 + 768 + h * 64 + d0 + tx];
    __syncthreads();
#pragma unroll
    for (int i = 0; i < 4; i++)
        dst[((size_t)bh * 64 + d0 + ty + i * 8) * 2048 + t0 + tx] = tile[tx][ty + i * 8];
}

// ---------------------------------------------------------------------------
// gemm_bt: C[M][N] = A[M][K] @ Bt[N][K]^T (+bias). 128x128 tile, BK=32, 4 waves.
// global_load_lds staging (16B) into XOR-swizzled unpadded LDS:
//   physical chunk p of row r holds logical k-chunk p^(r&3)  (chunks of 8 bf16)
// ---------------------------------------------------------------------------
template <bool F32OUT>
__global__ __launch_bounds__(256, 2)
void gemm_bt(const bf16_t* __restrict__ A, const bf16_t* __restrict__ Bt,
             void* __restrict__ Cv, int M, int N, int K, const float* __restrict__ bias) {
    __shared__ __align__(16) bf16_t As[128 * 32];
    __shared__ __align__(16) bf16_t Bs[128 * 32];
    const int tid = threadIdx.x;
    const int wave = tid >> 6, lane = tid & 63;
    const int wm = wave >> 1, wn = wave & 1;
    const int quad = lane >> 4, l16 = lane & 15;
    const int row0 = blockIdx.y * 128, col0 = blockIdx.x * 128;
    const int swz = l16 & 3;

    floatx4 acc[4][4];
#pragma unroll
    for (int i = 0; i < 4; i++)
#pragma unroll
        for (int j = 0; j < 4; j++) acc[i][j] = (floatx4){0.f, 0.f, 0.f, 0.f};

    for (int k0 = 0; k0 < K; k0 += 32) {
#pragma unroll
        for (int it = 0; it < 2; it++) {
            int cb = wave * 64 + it * 256;       // wave-uniform chunk base
            int c = cb + lane;                   // this lane's chunk (of 512)
            int r = c >> 2;
            int col = k0 + (((c & 3) ^ (r & 3)) * 8);
            async_copy16(A + (size_t)(row0 + r) * K + col, As + cb * 8);
            async_copy16(Bt + (size_t)(col0 + r) * K + col, Bs + cb * 8);
        }
        __syncthreads();
        bf16x8 af[4], bfr[4];
#pragma unroll
        for (int i = 0; i < 4; i++)
            af[i] = *(const bf16x8*)(As + (wm * 64 + i * 16 + l16) * 32 + ((quad ^ swz) * 8));
#pragma unroll
        for (int j = 0; j < 4; j++)
            bfr[j] = *(const bf16x8*)(Bs + (wn * 64 + j * 16 + l16) * 32 + ((quad ^ swz) * 8));
#pragma unroll
        for (int i = 0; i < 4; i++)
#pragma unroll
            for (int j = 0; j < 4; j++) acc[i][j] = MFMA16(af[i], bfr[j], acc[i][j]);
        __syncthreads();
    }
#pragma unroll
    for (int i = 0; i < 4; i++) {
#pragma unroll
        for (int j = 0; j < 4; j++) {
            int col = col0 + wn * 64 + j * 16 + l16;
            float bv = bias ? bias[col] : 0.0f;
#pragma unroll
            for (int r = 0; r < 4; r++) {
                int row = row0 + wm * 64 + i * 16 + quad * 4 + r;
                float v = acc[i][j][r] + bv;
                if (F32OUT)
                    ((float*)Cv)[(size_t)row * N + col] = v;
                else
                    ((bf16_t*)Cv)[(size_t)row * N + col] = (bf16_t)v;
            }
        }
    }
}

// ---------------------------------------------------------------------------
// attn: stage one 64x64 tile (rows at gtile + r*stride) into swizzled LDS
// ---------------------------------------------------------------------------
__device__ __forceinline__ void stage64(const bf16_t* __restrict__ gtile, int stride,
                                        bf16_t* lds, int wave, int lane) {
#pragma unroll
    for (int it = 0; it < 2; it++) {
        int cb = wave * 64 + it * 256;           // wave-uniform chunk base
        int c = cb + lane;                       // chunk of 512 (16B each)
        int r = c >> 3;
        int col = ((c & 7) ^ (r & 7)) * 8;       // XOR swizzle on global side
        async_copy16(gtile + (size_t)r * stride + col, lds + cb * 8);
    }
}

// one flash-attention step for 16 q-rows x 64 kv (per wave), exp2-domain softmax
__device__ __forceinline__ void attn_step(const bf16_t* __restrict__ kb,
                                          const bf16_t* __restrict__ vb,
                                          bf16_t* __restrict__ psw,
                                          bf16x8 qf0, bf16x8 qf1,
                                          floatx4* o, float* m_run, float* l_run,
                                          bool diag, int wave, int quad, int l16) {
    const int swz = l16 & 7;
    floatx4 s[4];
#pragma unroll
    for (int nt = 0; nt < 4; nt++) {
        const bf16_t* krow = kb + (nt * 16 + l16) * 64;
        bf16x8 kf0 = *(const bf16x8*)(krow + ((quad ^ swz) * 8));
        bf16x8 kf1 = *(const bf16x8*)(krow + (((quad + 4) ^ swz) * 8));
        s[nt] = (floatx4){0.f, 0.f, 0.f, 0.f};
        s[nt] = MFMA16(qf0, kf0, s[nt]);
        s[nt] = MFMA16(qf1, kf1, s[nt]);
    }
    if (diag) {
#pragma unroll
        for (int nt = 0; nt < 4; nt++)
#pragma unroll
            for (int r = 0; r < 4; r++)
                if (nt * 16 + l16 > wave * 16 + quad * 4 + r) s[nt][r] = -1e30f;
    }
    float mx[4];
#pragma unroll
    for (int r = 0; r < 4; r++)
        mx[r] = fmaxf(fmaxf(s[0][r], s[1][r]), fmaxf(s[2][r], s[3][r]));
#pragma unroll
    for (int off = 8; off; off >>= 1)
#pragma unroll
        for (int r = 0; r < 4; r++) mx[r] = fmaxf(mx[r], __shfl_xor(mx[r], off));
    float alpha[4], rs[4];
#pragma unroll
    for (int r = 0; r < 4; r++) {
        float mn = fmaxf(m_run[r], mx[r]);
        alpha[r] = EXP2F(m_run[r] - mn);
        m_run[r] = mn;
        rs[r] = 0.f;
    }
#pragma unroll
    for (int nt = 0; nt < 4; nt++)
#pragma unroll
        for (int r = 0; r < 4; r++) {
            float p = EXP2F(s[nt][r] - m_run[r]);
            s[nt][r] = p;
            rs[r] += p;
        }
#pragma unroll
    for (int off = 8; off; off >>= 1)
#pragma unroll
        for (int r = 0; r < 4; r++) rs[r] += __shfl_xor(rs[r], off);
#pragma unroll
    for (int r = 0; r < 4; r++) l_run[r] = l_run[r] * alpha[r] + rs[r];
#pragma unroll
    for (int nt = 0; nt < 4; nt++)
#pragma unroll
        for (int r = 0; r < 4; r++) o[nt][r] *= alpha[r];

    // P: C-layout -> per-wave LDS (swizzled) -> A-layout. Per-wave, no barrier.
#pragma unroll
    for (int nt = 0; nt < 4; nt++) {
        int chunk = nt * 2 + (l16 >> 3);
#pragma unroll
        for (int r = 0; r < 4; r++) {
            int rowP = quad * 4 + r;
            psw[rowP * 64 + ((chunk ^ (rowP & 7)) * 8) + (l16 & 7)] = (bf16_t)s[nt][r];
        }
    }
    asm volatile("s_waitcnt lgkmcnt(0)" ::: "memory");  // order P write->read (same wave)
    bf16x8 pf0 = *(const bf16x8*)(psw + l16 * 64 + ((quad ^ swz) * 8));
    bf16x8 pf1 = *(const bf16x8*)(psw + l16 * 64 + (((quad + 4) ^ swz) * 8));
#pragma unroll
    for (int nt = 0; nt < 4; nt++) {
        const bf16_t* vrow = vb + (nt * 16 + l16) * 64;
        bf16x8 vf0 = *(const bf16x8*)(vrow + ((quad ^ swz) * 8));
        bf16x8 vf1 = *(const bf16x8*)(vrow + (((quad + 4) ^ swz) * 8));
        o[nt] = MFMA16(pf0, vf0, o[nt]);
        o[nt] = MFMA16(pf1, vf1, o[nt]);
    }
}

// ---------------------------------------------------------------------------
// attn_kernel: causal flash attention. Block bx handles q-tiles {bx, 31-bx}
// (balanced 33 tile-computes/block) sharing staged K/V; double-buffered async
// staging, ONE barrier per kv-tile.
// ---------------------------------------------------------------------------
__global__ __launch_bounds__(256, 3)
void attn_kernel(const bf16_t* __restrict__ qkv, const bf16_t* __restrict__ Vt,
                 bf16_t* __restrict__ attn_out) {
    constexpr int T = 2048, C3 = 1152;
    const int bx = blockIdx.x, h = blockIdx.y, b = blockIdx.z;
    const int qa = bx, qb = 31 - bx;
    const int tid = threadIdx.x;
    const int wave = tid >> 6, lane = tid & 63;
    const int quad = lane >> 4, l16 = lane & 15;

    __shared__ __align__(16) bf16_t Ks[2][64 * 64];
    __shared__ __align__(16) bf16_t Vs[2][64 * 64];
    __shared__ __align__(16) bf16_t Ps[4][16 * 64];

    const bf16_t* kbase = qkv + (size_t)b * T * C3 + 384 + h * 64;  // K section
    const bf16_t* vbase = Vt + ((size_t)(b * 6 + h)) * 64 * T;      // V^T [d][t]

    // Q fragments for both phases (A-operand layout), log2-scaled via weights
    const bf16_t* qpa =
        qkv + ((size_t)b * T + qa * 64 + wave * 16 + l16) * C3 + h * 64 + quad * 8;
    const bf16_t* qpb =
        qkv + ((size_t)b * T + qb * 64 + wave * 16 + l16) * C3 + h * 64 + quad * 8;
    bf16x8 qA0 = *(const bf16x8*)qpa, qA1 = *(const bf16x8*)(qpa + 32);
    bf16x8 qB0 = *(const bf16x8*)qpb, qB1 = *(const bf16x8*)(qpb + 32);

    floatx4 oA[4], oB[4];
    float mA[4], lA[4], mB[4], lB[4];
#pragma unroll
    for (int r = 0; r < 4; r++) {
        oA[r] = (floatx4){0.f, 0.f, 0.f, 0.f};
        oB[r] = (floatx4){0.f, 0.f, 0.f, 0.f};
        mA[r] = mB[r] = -1e30f;
        lA[r] = lB[r] = 0.f;
    }

    // prologue: stage kt=0 into buffer 0
    stage64(kbase, C3, &Ks[0][0], wave, lane);
    stage64(vbase, T, &Vs[0][0], wave, lane);

    for (int kt = 0; kt <= qb; kt++) {
        __syncthreads();  // completes staging of buf[kt&1]; releases buf[(kt+1)&1]
        if (kt < qb) {
            stage64(kbase + (size_t)(kt + 1) * 64 * C3, C3, &Ks[(kt + 1) & 1][0], wave, lane);
            stage64(vbase + (kt + 1) * 64, T, &Vs[(kt + 1) & 1][0], wave, lane);
        }
        const bf16_t* kb = &Ks[kt & 1][0];
        const bf16_t* vb = &Vs[kt & 1][0];
        if (kt <= qa)
            attn_step(kb, vb, &Ps[wave][0], qA0, qA1, oA, mA, lA, kt == qa, wave, quad, l16);
        attn_step(kb, vb, &Ps[wave][0], qB0, qB1, oB, mB, lB, kt == qb, wave, quad, l16);
    }

    // epilogue: normalize and store both q-tiles
#pragma unroll
    for (int nt = 0; nt < 4; nt++)
#pragma unroll
        for (int r = 0; r < 4; r++) {
            int col = h * 64 + nt * 16 + l16;
            int tA = qa * 64 + wave * 16 + quad * 4 + r;
            int tB = qb * 64 + wave * 16 + quad * 4 + r;
            attn_out[((size_t)b * T + tA) * 384 + col] = (bf16_t)(oA[nt][r] / lA[r]);
            attn_out[((size_t)b * T + tB) * 384 + col] = (bf16_t)(oB[nt][r] / lB[r]);
        }
}

// ---------------------------------------------------------------------------
extern "C" void kernel_launch(void* const* d_in, const int* in_sizes, int n_in,
                              void* d_out, int out_size, void* d_ws, size_t ws_size,
                              hipStream_t stream) {
    const float* x      = (const float*)d_in[0];  // [8,2048,384] fp32
    const float* w_qkv  = (const float*)d_in[1];  // [384,1152]  fp32
    const float* w_proj = (const float*)d_in[2];  // [384,384]   fp32
    const float* b_proj = (const float*)d_in[3];  // [384]       fp32
    float* out = (float*)d_out;                   // [8,2048,384] fp32

    bf16_t* ws = (bf16_t*)d_ws;
    bf16_t* wqkvT = ws;                                  // 1152*384
    bf16_t* wprojT = wqkvT + 1152 * 384;                 // 384*384
    bf16_t* xb = wprojT + 384 * 384;                     // 16384*384
    bf16_t* qkv = xb + (size_t)16384 * 384;              // 16384*1152
    bf16_t* Vt = qkv + (size_t)16384 * 1152;             // 48*64*2048
    bf16_t* attn = Vt + (size_t)48 * 64 * 2048;          // 16384*384

    hipLaunchKernelGGL(cast_f32_bf16, dim3(16384 * 384 / 4 / 256), dim3(256), 0, stream,
                       x, xb);
    hipLaunchKernelGGL(prep_w, dim3(36, 12, 2), dim3(256), 0, stream,
                       w_qkv, w_proj, wqkvT, wprojT);
    hipLaunchKernelGGL((gemm_bt<false>), dim3(9, 128), dim3(256), 0, stream,
                       xb, wqkvT, (void*)qkv, 16384, 1152, 384, (const float*)nullptr);
    hipLaunchKernelGGL(vt_kernel, dim3(64, 2, 48), dim3(256), 0, stream, qkv, Vt);
    hipLaunchKernelGGL(attn_kernel, dim3(16, 6, 8), dim3(256), 0, stream, qkv, Vt, attn);
    hipLaunchKernelGGL((gemm_bt<true>), dim3(3, 128), dim3(256), 0, stream,
                       attn, wprojT, (void*)out, 16384, 384, 384, b_proj);
}

// Round 4
// 192.385 us; speedup vs baseline: 1.5888x; 1.1586x over previous
//
#include <hip/hip_runtime.h>
#include <hip/hip_bf16.h>

typedef __bf16 bf16_t;
typedef __bf16 bf16x8 __attribute__((ext_vector_type(8)));
typedef __bf16 bf16x4 __attribute__((ext_vector_type(4)));
typedef float floatx4 __attribute__((ext_vector_type(4)));

#define MFMA16(a, b, c) __builtin_amdgcn_mfma_f32_16x16x32_bf16(a, b, c, 0, 0, 0)

#if __has_builtin(__builtin_amdgcn_exp2f)
#define EXP2F(x) __builtin_amdgcn_exp2f(x)
#else
#define EXP2F(x) __expf((x)*0.693147180559945f)
#endif

// async global->LDS, 16B per lane. LDS dest = wave-uniform base + lane*16.
__device__ __forceinline__ void async_copy16(const bf16_t* g, bf16_t* l) {
    __builtin_amdgcn_global_load_lds((const __attribute__((address_space(1))) void*)g,
                                     (__attribute__((address_space(3))) void*)l, 16, 0, 0);
}

// ---------------------------------------------------------------------------
// cast_f32_bf16: x (fp32) -> xb (bf16), 4 elems/thread
// ---------------------------------------------------------------------------
__global__ void cast_f32_bf16(const float* __restrict__ in, bf16_t* __restrict__ out) {
    int i = blockIdx.x * blockDim.x + threadIdx.x;
    float4 v = ((const float4*)in)[i];
    bf16x4 o = {(bf16_t)v.x, (bf16_t)v.y, (bf16_t)v.z, (bf16_t)v.w};
    *(bf16x4*)(out + (size_t)i * 4) = o;
}

// ---------------------------------------------------------------------------
// prep_w (fp32 in, bf16 out):
//   wqkvT[n][k] = w_qkv[k][n] * (n<384 ? 0.125*log2(e) : 1)
//   wprojT[n][k] = w_proj[k][n]
// ---------------------------------------------------------------------------
__global__ void prep_w(const float* __restrict__ w_qkv, const float* __restrict__ w_proj,
                       bf16_t* __restrict__ wqkvT, bf16_t* __restrict__ wprojT) {
    __shared__ float tile[32][33];
    const int which = blockIdx.z;             // 0: w_qkv, 1: w_proj
    const int Nd = which ? 384 : 1152;
    const int n0 = blockIdx.x * 32, k0 = blockIdx.y * 32;
    if (n0 >= Nd) return;
    const float* in = which ? w_proj : w_qkv;
    bf16_t* out = which ? wprojT : wqkvT;
    const int tx = threadIdx.x & 31, ty = threadIdx.x >> 5;  // ty in [0,8)
#pragma unroll
    for (int i = 0; i < 4; i++)
        tile[ty + i * 8][tx] = in[(size_t)(k0 + ty + i * 8) * Nd + n0 + tx];
    __syncthreads();
#pragma unroll
    for (int i = 0; i < 4; i++) {
        int n = n0 + ty + i * 8;
        float v = tile[tx][ty + i * 8];
        if (!which && n < 384) v *= 0.1803368851f;  // 0.125 * log2(e)
        out[(size_t)n * 384 + k0 + tx] = (bf16_t)v;
    }
}

// ---------------------------------------------------------------------------
// vt_kernel: Vt[b][h][d][t] = qkv[b][t][768 + h*64 + d]
// ---------------------------------------------------------------------------
__global__ void vt_kernel(const bf16_t* __restrict__ qkv, bf16_t* __restrict__ Vt) {
    __shared__ unsigned short tile[32][33];
    const int t0 = blockIdx.x * 32, d0 = blockIdx.y * 32;
    const int bh = blockIdx.z;  // b*6+h
    const int b = bh / 6, h = bh % 6;
    const int tx = threadIdx.x & 31, ty = threadIdx.x >> 5;
    const unsigned short* src = (const unsigned short*)qkv;
    unsigned short* dst = (unsigned short*)Vt;
#pragma unroll
    for (int i = 0; i < 4; i++)
        tile[ty + i * 8][tx] =
            src[((size_t)b * 2048 + t0 + ty + i * 8) * 1152 + 768 + h * 64 + d0 + tx];
    __syncthreads();
#pragma unroll
    for (int i = 0; i < 4; i++)
        dst[((size_t)bh * 64 + d0 + ty + i * 8) * 2048 + t0 + tx] = tile[tx][ty + i * 8];
}

// ---------------------------------------------------------------------------
// gemm_bt: C[M][N] = A[M][K] @ Bt[N][K]^T (+bias). 128x128 tile, BK=32, 4 waves.
// DOUBLE-BUFFERED: async global_load_lds prefetch of k-tile kt+1 overlaps the
// MFMA compute of kt; ONE barrier per iteration. XOR-swizzled unpadded LDS.
// ---------------------------------------------------------------------------
template <bool F32OUT>
__global__ __launch_bounds__(256, 2)
void gemm_bt(const bf16_t* __restrict__ A, const bf16_t* __restrict__ Bt,
             void* __restrict__ Cv, int M, int N, int K, const float* __restrict__ bias) {
    __shared__ __align__(16) bf16_t As[2][128 * 32];
    __shared__ __align__(16) bf16_t Bs[2][128 * 32];
    const int tid = threadIdx.x;
    const int wave = tid >> 6, lane = tid & 63;
    const int wm = wave >> 1, wn = wave & 1;
    const int quad = lane >> 4, l16 = lane & 15;
    const int row0 = blockIdx.y * 128, col0 = blockIdx.x * 128;
    const int swz = l16 & 3;

    floatx4 acc[4][4];
#pragma unroll
    for (int i = 0; i < 4; i++)
#pragma unroll
        for (int j = 0; j < 4; j++) acc[i][j] = (floatx4){0.f, 0.f, 0.f, 0.f};

    auto stage = [&](int buf, int k0) {
#pragma unroll
        for (int it = 0; it < 2; it++) {
            int cb = wave * 64 + it * 256;       // wave-uniform chunk base
            int c = cb + lane;                   // this lane's chunk (of 512)
            int r = c >> 2;
            int col = k0 + (((c & 3) ^ (r & 3)) * 8);
            async_copy16(A + (size_t)(row0 + r) * K + col, &As[buf][0] + cb * 8);
            async_copy16(Bt + (size_t)(col0 + r) * K + col, &Bs[buf][0] + cb * 8);
        }
    };

    const int nk = K >> 5;
    stage(0, 0);
    for (int kt = 0; kt < nk; kt++) {
        __syncthreads();  // completes staging of buf[kt&1]
        if (kt + 1 < nk) stage((kt + 1) & 1, (kt + 1) * 32);
        const bf16_t* as = &As[kt & 1][0];
        const bf16_t* bs = &Bs[kt & 1][0];
        bf16x8 af[4], bfr[4];
#pragma unroll
        for (int i = 0; i < 4; i++)
            af[i] = *(const bf16x8*)(as + (wm * 64 + i * 16 + l16) * 32 + ((quad ^ swz) * 8));
#pragma unroll
        for (int j = 0; j < 4; j++)
            bfr[j] = *(const bf16x8*)(bs + (wn * 64 + j * 16 + l16) * 32 + ((quad ^ swz) * 8));
#pragma unroll
        for (int i = 0; i < 4; i++)
#pragma unroll
            for (int j = 0; j < 4; j++) acc[i][j] = MFMA16(af[i], bfr[j], acc[i][j]);
    }
#pragma unroll
    for (int i = 0; i < 4; i++) {
#pragma unroll
        for (int j = 0; j < 4; j++) {
            int col = col0 + wn * 64 + j * 16 + l16;
            float bv = bias ? bias[col] : 0.0f;
#pragma unroll
            for (int r = 0; r < 4; r++) {
                int row = row0 + wm * 64 + i * 16 + quad * 4 + r;
                float v = acc[i][j][r] + bv;
                if (F32OUT)
                    ((float*)Cv)[(size_t)row * N + col] = v;
                else
                    ((bf16_t*)Cv)[(size_t)row * N + col] = (bf16_t)v;
            }
        }
    }
}

// ---------------------------------------------------------------------------
// attn: stage one 64x64 tile into XOR-swizzled LDS (16B chunk ^= row&7)
// ---------------------------------------------------------------------------
__device__ __forceinline__ void stage64(const bf16_t* __restrict__ gtile, int stride,
                                        bf16_t* lds, int wave, int lane) {
#pragma unroll
    for (int it = 0; it < 2; it++) {
        int cb = wave * 64 + it * 256;           // wave-uniform chunk base
        int c = cb + lane;                       // chunk of 512 (16B each)
        int r = c >> 3;
        int col = ((c & 7) ^ (r & 7)) * 8;       // XOR swizzle on global side
        async_copy16(gtile + (size_t)r * stride + col, lds + cb * 8);
    }
}

// ---------------------------------------------------------------------------
// attn_tile: one flash step for ONE 16-row q-tile against 64 kv, with K/V
// fragments passed in (shared across the block's two q-tiles).
// S^T = mfma(K, Q): rows kv=quad*4+r, cols q=l16 -> softmax state is per-lane
// scalar. O^T = mfma(V^T, P^T): rows d, cols q=l16 -> alpha/l need no shuffles.
// P^T round-trip: 4 ds_write_b64 + 2 ds_read_b128 into per-wave swizzled LDS.
// ---------------------------------------------------------------------------
__device__ __forceinline__ void attn_tile(const bf16x8 kf[4][2], const bf16x8 vf[4][2],
                                          bf16_t* __restrict__ psw,
                                          bf16x8 qf0, bf16x8 qf1,
                                          floatx4* o, float& m_run, float& l_run,
                                          bool diag, int wave, int quad, int l16) {
    const int swz = l16 & 7;
    floatx4 s[4];
#pragma unroll
    for (int nt = 0; nt < 4; nt++) {
        s[nt] = (floatx4){0.f, 0.f, 0.f, 0.f};
        s[nt] = MFMA16(kf[nt][0], qf0, s[nt]);   // A=K (m=kv), B=Q^T (n=q)
        s[nt] = MFMA16(kf[nt][1], qf1, s[nt]);
    }
    if (diag) {
#pragma unroll
        for (int nt = 0; nt < 4; nt++)
#pragma unroll
            for (int r = 0; r < 4; r++)
                if (nt * 16 + quad * 4 + r > wave * 16 + l16) s[nt][r] = -1e30f;
    }
    // per-lane q-row: local max over 16 kv + 2 shuffles across quads
    float mx = -1e30f;
#pragma unroll
    for (int nt = 0; nt < 4; nt++)
#pragma unroll
        for (int r = 0; r < 4; r++) mx = fmaxf(mx, s[nt][r]);
    mx = fmaxf(mx, __shfl_xor(mx, 16));
    mx = fmaxf(mx, __shfl_xor(mx, 32));
    float mn = fmaxf(m_run, mx);
    float alpha = EXP2F(m_run - mn);
    m_run = mn;
    float rs = 0.f;
#pragma unroll
    for (int nt = 0; nt < 4; nt++)
#pragma unroll
        for (int r = 0; r < 4; r++) {
            float p = EXP2F(s[nt][r] - mn);
            s[nt][r] = p;
            rs += p;
        }
    rs += __shfl_xor(rs, 16);
    rs += __shfl_xor(rs, 32);
    l_run = l_run * alpha + rs;
#pragma unroll
    for (int dt = 0; dt < 4; dt++)
#pragma unroll
        for (int r = 0; r < 4; r++) o[dt][r] *= alpha;

    // P^T -> per-wave LDS [q=l16][kv], swizzled; 4x b64 writes
#pragma unroll
    for (int nt = 0; nt < 4; nt++) {
        bf16x4 p4 = {(bf16_t)s[nt][0], (bf16_t)s[nt][1], (bf16_t)s[nt][2], (bf16_t)s[nt][3]};
        *(bf16x4*)(psw + l16 * 64 + (((nt * 2 + (quad >> 1)) ^ swz) * 8) + (quad & 1) * 4) = p4;
    }
    asm volatile("s_waitcnt lgkmcnt(0)" ::: "memory");  // same-wave write->read
    bf16x8 pf0 = *(const bf16x8*)(psw + l16 * 64 + ((quad ^ swz) * 8));
    bf16x8 pf1 = *(const bf16x8*)(psw + l16 * 64 + (((4 + quad) ^ swz) * 8));
    // O^T += V^T @ P^T : A=V^T (m=d), B=P^T (n=q)
#pragma unroll
    for (int dt = 0; dt < 4; dt++) {
        o[dt] = MFMA16(vf[dt][0], pf0, o[dt]);
        o[dt] = MFMA16(vf[dt][1], pf1, o[dt]);
    }
}

// ---------------------------------------------------------------------------
// attn_kernel: causal flash attention. Block bx handles q-tiles {bx, 31-bx}
// sharing BOTH the staged K/V tiles AND the K/V register fragments.
// Double-buffered async staging, one barrier per kv-tile.
// ---------------------------------------------------------------------------
__global__ __launch_bounds__(256, 2)
void attn_kernel(const bf16_t* __restrict__ qkv, const bf16_t* __restrict__ Vt,
                 bf16_t* __restrict__ attn_out) {
    constexpr int T = 2048, C3 = 1152;
    const int bx = blockIdx.x, h = blockIdx.y, b = blockIdx.z;
    const int qa = bx, qb = 31 - bx;
    const int tid = threadIdx.x;
    const int wave = tid >> 6, lane = tid & 63;
    const int quad = lane >> 4, l16 = lane & 15;

    __shared__ __align__(16) bf16_t Ks[2][64 * 64];
    __shared__ __align__(16) bf16_t Vs[2][64 * 64];
    __shared__ __align__(16) bf16_t Ps[4][16 * 64];

    const bf16_t* kbase = qkv + (size_t)b * T * C3 + 384 + h * 64;  // K section
    const bf16_t* vbase = Vt + ((size_t)(b * 6 + h)) * 64 * T;      // V^T [d][t]

    // Q fragments for both q-tiles (B-operand layout: n=q=l16, k=d), log2-scaled
    const bf16_t* qpa =
        qkv + ((size_t)b * T + qa * 64 + wave * 16 + l16) * C3 + h * 64 + quad * 8;
    const bf16_t* qpb =
        qkv + ((size_t)b * T + qb * 64 + wave * 16 + l16) * C3 + h * 64 + quad * 8;
    bf16x8 qA0 = *(const bf16x8*)qpa, qA1 = *(const bf16x8*)(qpa + 32);
    bf16x8 qB0 = *(const bf16x8*)qpb, qB1 = *(const bf16x8*)(qpb + 32);

    floatx4 oA[4], oB[4];
    float mA = -1e30f, lA = 0.f, mB = -1e30f, lB = 0.f;
#pragma unroll
    for (int r = 0; r < 4; r++) {
        oA[r] = (floatx4){0.f, 0.f, 0.f, 0.f};
        oB[r] = (floatx4){0.f, 0.f, 0.f, 0.f};
    }

    stage64(kbase, C3, &Ks[0][0], wave, lane);
    stage64(vbase, T, &Vs[0][0], wave, lane);

    const int swz = l16 & 7;
    for (int kt = 0; kt <= qb; kt++) {
        __syncthreads();  // completes staging of buf[kt&1]
        if (kt < qb) {
            stage64(kbase + (size_t)(kt + 1) * 64 * C3, C3, &Ks[(kt + 1) & 1][0], wave, lane);
            stage64(vbase + (kt + 1) * 64, T, &Vs[(kt + 1) & 1][0], wave, lane);
        }
        const bf16_t* kb = &Ks[kt & 1][0];
        const bf16_t* vb = &Vs[kt & 1][0];
        // shared fragments: K as A-operand (m=kv), V^T as A-operand (m=d)
        bf16x8 kf[4][2], vf[4][2];
#pragma unroll
        for (int nt = 0; nt < 4; nt++)
#pragma unroll
            for (int hh = 0; hh < 2; hh++) {
                kf[nt][hh] = *(const bf16x8*)(kb + (nt * 16 + l16) * 64 +
                                              (((hh * 4 + quad) ^ swz) * 8));
                vf[nt][hh] = *(const bf16x8*)(vb + (nt * 16 + l16) * 64 +
                                              (((hh * 4 + quad) ^ swz) * 8));
            }
        if (kt <= qa)
            attn_tile(kf, vf, &Ps[wave][0], qA0, qA1, oA, mA, lA, kt == qa, wave, quad, l16);
        attn_tile(kf, vf, &Ps[wave][0], qB0, qB1, oB, mB, lB, kt == qb, wave, quad, l16);
    }

    // epilogue: O^T layout -> lane holds O[q=l16][d=dt*16+quad*4+r]
    const float invA = 1.0f / lA, invB = 1.0f / lB;
    const int tA = qa * 64 + wave * 16 + l16, tB = qb * 64 + wave * 16 + l16;
#pragma unroll
    for (int dt = 0; dt < 4; dt++) {
        bf16x4 va = {(bf16_t)(oA[dt][0] * invA), (bf16_t)(oA[dt][1] * invA),
                     (bf16_t)(oA[dt][2] * invA), (bf16_t)(oA[dt][3] * invA)};
        bf16x4 vb4 = {(bf16_t)(oB[dt][0] * invB), (bf16_t)(oB[dt][1] * invB),
                      (bf16_t)(oB[dt][2] * invB), (bf16_t)(oB[dt][3] * invB)};
        int col = h * 64 + dt * 16 + quad * 4;
        *(bf16x4*)(attn_out + ((size_t)b * T + tA) * 384 + col) = va;
        *(bf16x4*)(attn_out + ((size_t)b * T + tB) * 384 + col) = vb4;
    }
}

// ---------------------------------------------------------------------------
extern "C" void kernel_launch(void* const* d_in, const int* in_sizes, int n_in,
                              void* d_out, int out_size, void* d_ws, size_t ws_size,
                              hipStream_t stream) {
    const float* x      = (const float*)d_in[0];  // [8,2048,384] fp32
    const float* w_qkv  = (const float*)d_in[1];  // [384,1152]  fp32
    const float* w_proj = (const float*)d_in[2];  // [384,384]   fp32
    const float* b_proj = (const float*)d_in[3];  // [384]       fp32
    float* out = (float*)d_out;                   // [8,2048,384] fp32

    bf16_t* ws = (bf16_t*)d_ws;
    bf16_t* wqkvT = ws;                                  // 1152*384
    bf16_t* wprojT = wqkvT + 1152 * 384;                 // 384*384
    bf16_t* xb = wprojT + 384 * 384;                     // 16384*384
    bf16_t* qkv = xb + (size_t)16384 * 384;              // 16384*1152
    bf16_t* Vt = qkv + (size_t)16384 * 1152;             // 48*64*2048
    bf16_t* attn = Vt + (size_t)48 * 64 * 2048;          // 16384*384

    hipLaunchKernelGGL(cast_f32_bf16, dim3(16384 * 384 / 4 / 256), dim3(256), 0, stream,
                       x, xb);
    hipLaunchKernelGGL(prep_w, dim3(36, 12, 2), dim3(256), 0, stream,
                       w_qkv, w_proj, wqkvT, wprojT);
    hipLaunchKernelGGL((gemm_bt<false>), dim3(9, 128), dim3(256), 0, stream,
                       xb, wqkvT, (void*)qkv, 16384, 1152, 384, (const float*)nullptr);
    hipLaunchKernelGGL(vt_kernel, dim3(64, 2, 48), dim3(256), 0, stream, qkv, Vt);
    hipLaunchKernelGGL(attn_kernel, dim3(16, 6, 8), dim3(256), 0, stream, qkv, Vt, attn);
    hipLaunchKernelGGL((gemm_bt<true>), dim3(3, 128), dim3(256), 0, stream,
                       attn, wprojT, (void*)out, 16384, 384, 384, b_proj);
}